// Round 3
// baseline (103.326 us; speedup 1.0000x reference)
//
#include <hip/hip_runtime.h>
#include <math.h>

#define POOL 7
#define FH 50
#define FW 50
#define FC 1024
#define FC4 (FC / 4)        // 256 float4 groups per spatial cell
#define CHUNKS 4            // channel chunks; 64 float4 (256 ch) per chunk
#define F4C 64              // float4 per cell per chunk (one wave-wide load)
#define ROWSTRIDE (FW * FC4)
#define JGROUPS 4           // column-bin groups: {0,1},{2,3},{4,5},{6}
#define UNITS_PER_ROI (POOL * JGROUPS)   // 28
#define PREF 8              // load-pipeline depth (8 x vf4 = 32 VGPR)

typedef float vf4 __attribute__((ext_vector_type(4)));

static __device__ __forceinline__ vf4 vmax4(vf4 a, vf4 b) {
    vf4 r;
    r.x = fmaxf(a.x, b.x);
    r.y = fmaxf(a.y, b.y);
    r.z = fmaxf(a.z, b.z);
    r.w = fmaxf(a.w, b.w);
    return r;
}

// XCD-partitioned RoI max-pool with a deep per-wave load pipeline.
//
// Rounds 0 and 2 (very different decompositions) both issued ~422K 1KB
// wave-loads and both landed at ~46 us = ~28 cy/load/CU = 15 B/cy/CU of
// L2-read throughput. hipBLASLt sustains 51 B/cy/CU on this chip, so the
// limiter is NOT the read path but our in-flight load count: acc-chained
// runtime loops force vmcnt(0)-ish waits every 1-2 loads.
//
// This version keeps round 2's grid exactly (8400 blocks, 33,600 waves,
// wave = (roi, row-bin i, col-bin-pair jg, chunk), chunk = b&3 pinned per
// XCD so each XCD's 2.56 MB fm slice stays L2-resident — FETCH_SIZE 8.3 MB
// confirmed) and changes ONLY the inner loop: a flattened, statically
// indexed 8-deep rotating load pipeline over the wave's (rows x span) cell
// list. buf[] is only indexed with compile-time constants inside fully
// unrolled loops -> stays in registers; consuming buf[k] then immediately
// reissuing slot k makes the compiler emit counted vmcnt waits with ~8
// loads in flight per wave.
//
// Fast path: wstep >= 1 (always, rw >= 9 here) means col bins exactly
// partition [0, rw) with no empty-bin adjustment, so a cell's bin within
// the pair is one wave-uniform compare against the split column.
__global__ __launch_bounds__(256) void roipool_kernel(
    const float* __restrict__ fm,     // [FH, FW, FC]
    const float* __restrict__ rois,   // [N, 4] (y1, x1, y2, x2) normalized
    float* __restrict__ out,          // [N, 7, 7, FC]
    int nunits)                       // N * POOL * JGROUPS units
{
    const int b     = blockIdx.x;
    const int chunk = b & (CHUNKS - 1);       // pinned per XCD (b%8 round-robin)
    const int wave  = threadIdx.x >> 6;
    const int lane  = threadIdx.x & 63;
    const int u     = (b >> 2) * 4 + wave;    // ((n*7 + i)*4 + jg)
    if (u >= nunits) return;

    const int n   = u / UNITS_PER_ROI;
    const int rem = u - n * UNITS_PER_ROI;
    const int i   = rem >> 2;
    const int jg  = rem & 3;
    const int j0  = jg * 2;                   // first col bin of this group
    const int jcnt = (jg < JGROUPS - 1) ? 2 : 1;

    // ROI corners: truncating float->int cast, matching jnp astype(int32)
    const float4 roi = reinterpret_cast<const float4*>(rois)[n];
    const int h0 = (int)((float)FH * roi.x);
    const int w0 = (int)((float)FW * roi.y);
    const int h1 = (int)((float)FH * roi.z);
    const int w1 = (int)((float)FW * roi.w);
    const int rh = h1 - h0;
    const int rw = w1 - w0;
    const int hstep = rh / POOL;
    const int wstep = rw / POOL;

    // row-bin bounds (region-relative) + empty-bin adjustment
    int sh = i * hstep;
    int eh = (i < POOL - 1) ? (i + 1) * hstep : rh;
    if (sh == eh) { if (eh < rh) eh += 1; else sh -= 1; }
    const int r0 = max(0, h0 + sh);
    const int r1 = min(FH, h0 + eh);

    // this wave's float4 index within a cell for its pinned channel chunk
    const int f4 = chunk * F4C + lane;        // [0, 256)
    const vf4* fmbase = reinterpret_cast<const vf4*>(fm) + f4;
    vf4* o = reinterpret_cast<vf4*>(out) + (size_t)(n * 49 + i * 7 + j0) * FC4 + f4;

    vf4 a0 = {-INFINITY, -INFINITY, -INFINITY, -INFINITY};
    vf4 a1 = a0;

    if (wstep >= 1) {
        // ---- fast path: bins partition, no empty-bin adjustment ----
        // pair span [S, E), internal boundary at `split` (cells < split -> a0)
        const int S     = max(0, w0 + j0 * wstep);
        const int split = (jcnt == 2) ? (w0 + (j0 + 1) * wstep)
                                      : (w0 + rw);          // all cells -> a0
        const int Eraw  = (jcnt == 2)
                            ? ((j0 + 2 == POOL) ? (w0 + rw) : (w0 + (j0 + 2) * wstep))
                            : (w0 + rw);
        const int E     = min(FW, Eraw);

        const int span  = E - S;
        const int nrows = r1 - r0;
        const int total = (span > 0 && nrows > 0) ? span * nrows : 0;

        const vf4* qp = fmbase + r0 * ROWSTRIDE + S * FC4;  // issue cursor
        const int rowadj = ROWSTRIDE - span * FC4;

        vf4 buf[PREF];
        int qc = 0;                      // issue col index within span
#pragma unroll
        for (int k = 0; k < PREF; ++k) {
            if (k < total) {
                buf[k] = *qp;
                qp += FC4; if (++qc == span) { qc = 0; qp += rowadj; }
            }
        }
        int issued = (total < PREF) ? total : PREF;

        int ccol = S;                    // consume col cursor
        int consumed = 0;
        while (consumed + PREF <= total) {
#pragma unroll
            for (int k = 0; k < PREF; ++k) {
                vf4 v = buf[k];
                if (ccol < split) a0 = vmax4(a0, v); else a1 = vmax4(a1, v);
                if (++ccol == E) ccol = S;
                if (issued < total) {
                    buf[k] = *qp;
                    qp += FC4; if (++qc == span) { qc = 0; qp += rowadj; }
                    ++issued;
                }
            }
            consumed += PREF;
        }
        const int tail = total - consumed;
#pragma unroll
        for (int k = 0; k < PREF; ++k) {
            if (k < tail) {
                vf4 v = buf[k];
                if (ccol < split) a0 = vmax4(a0, v); else a1 = vmax4(a1, v);
                if (++ccol == E) ccol = S;
            }
        }
    } else {
        // ---- slow path (rw < 7; unreachable for this input distribution,
        //      kept for correctness): per-bin adjusted chained scan ----
        int c0[2], c1[2];
#pragma unroll
        for (int t = 0; t < 2; ++t) {
            const int j = j0 + t;
            if (j < POOL) {
                int sw = j * wstep;
                int ew = (j < POOL - 1) ? (j + 1) * wstep : rw;
                if (sw == ew) { if (ew < rw) ew += 1; else sw -= 1; }
                c0[t] = max(0, w0 + sw);
                c1[t] = min(FW, w0 + ew);
            } else {
                c0[t] = 0; c1[t] = 0;
            }
        }
        for (int r = r0; r < r1; ++r) {
            const vf4* rowp = fmbase + r * ROWSTRIDE;
#pragma unroll
            for (int t = 0; t < 2; ++t) {
                vf4 acc = (t == 0) ? a0 : a1;
                for (int c = c0[t]; c < c1[t]; ++c) {
                    acc = vmax4(acc, rowp[c * FC4]);
                }
                if (t == 0) a0 = acc; else a1 = acc;
            }
        }
    }

    __builtin_nontemporal_store(a0, o);
    if (jcnt == 2) {
        __builtin_nontemporal_store(a1, o + (size_t)FC4);
    }
}

extern "C" void kernel_launch(void* const* d_in, const int* in_sizes, int n_in,
                              void* d_out, int out_size, void* d_ws, size_t ws_size,
                              hipStream_t stream) {
    const float* features = (const float*)d_in[0];  // [1,50,50,1024]
    const float* rois     = (const float*)d_in[1];  // [N,4]
    float* out            = (float*)d_out;          // [N,7,7,1024]
    const int N = in_sizes[1] / 4;

    const int nunits = N * UNITS_PER_ROI;           // 8400 units
    // linear grid: block b -> chunk b&3 (XCD-pinned), units (b>>2)*4 + wave
    dim3 grid(((nunits + 3) / 4) * CHUNKS);         // 8400 blocks
    dim3 block(256);
    roipool_kernel<<<grid, block, 0, stream>>>(features, rois, out, nunits);
}

// Round 4
// 101.502 us; speedup vs baseline: 1.0180x; 1.0180x over previous
//
#include <hip/hip_runtime.h>
#include <math.h>

#define POOL 7
#define FH 50
#define FW 50
#define FC 1024
#define FC4 (FC / 4)        // 256 vf4 per spatial cell
#define CHUNKS 4            // channel chunks; 64 vf4 (256 ch) per chunk
#define F4C 64              // vf4 per cell per chunk (one wave-wide load)
#define NCELLS (FH * FW)    // 2500
#define CHSLAB (NCELLS * F4C)            // 160000 vf4 per chunk-major slab
#define JGROUPS 4           // column-bin groups: {0,1},{2,3},{4,5},{6}
#define UNITS_PER_ROI (POOL * JGROUPS)   // 28

typedef float vf4 __attribute__((ext_vector_type(4)));

static __device__ __forceinline__ vf4 vmax4(vf4 a, vf4 b) {
    vf4 r;
    r.x = fmaxf(a.x, b.x);
    r.y = fmaxf(a.y, b.y);
    r.z = fmaxf(a.z, b.z);
    r.w = fmaxf(a.w, b.w);
    return r;
}

// Pass 1: re-layout fm to chunk-major fmT[chunk][cell][256ch].
//
// Why: in the natural [cell][1024ch] layout, a pooling wave's cell loads
// stride 4096B with a FIXED intra-cell offset (chunk*1KB + lane*16), so
// addr[11:8] — the L2 channel-select granule bits — are identical for every
// cell the wave (and, with chunk pinning, the whole XCD) touches: all reads
// hit ~4 of 16 L2 channels. 34.5 TB/s * 4/16 = 8.6 TB/s; 433 MB / 8.6 TB/s
// = 50 us — matching the ~44 us invariant across rounds 0/2/3 regardless of
// per-wave structure. Chunk-major makes consecutive cells stride 1KB, so
// channel granules cycle fully every 4 cells.
__global__ __launch_bounds__(256) void chunkmajor_kernel(
    const float* __restrict__ fm,    // [2500][1024]
    float* __restrict__ fmT)         // [4][2500][256]
{
    const int b     = blockIdx.x;            // 625 cell-groups x 4 chunks
    const int chunk = b & (CHUNKS - 1);      // b%8 XCD round-robin -> slab
                                             // lands mostly on its reader XCDs
    const int cg    = b >> 2;
    const int cell  = cg * 4 + (threadIdx.x >> 6);
    const int lane  = threadIdx.x & 63;
    const vf4 v = reinterpret_cast<const vf4*>(fm)[(size_t)cell * FC4 + chunk * F4C + lane];
    reinterpret_cast<vf4*>(fmT)[(size_t)chunk * CHSLAB + (size_t)cell * F4C + lane] = v;
}

// Pass 2: round-2's proven kernel (8400 blocks, wave = (roi, row-bin,
// col-bin-pair, chunk), chunk = b&3 pinned per XCD, 2.56 MB slab
// L2-resident) — ONLY the source addressing is changed, via compile-time
// strides: CSTRIDE = vf4 between cells, CHSTRIDE = vf4 between chunks.
template<int CSTRIDE, int CHSTRIDE>
__global__ __launch_bounds__(256) void roipool_kernel(
    const float* __restrict__ src,    // fm (direct) or fmT (chunk-major)
    const float* __restrict__ rois,   // [N, 4] (y1, x1, y2, x2) normalized
    float* __restrict__ out,          // [N, 7, 7, FC]
    int nunits)                       // N * POOL * JGROUPS units
{
    const int b     = blockIdx.x;
    const int chunk = b & (CHUNKS - 1);       // pinned per XCD (b%8 round-robin)
    const int wave  = threadIdx.x >> 6;
    const int lane  = threadIdx.x & 63;
    const int u     = (b >> 2) * 4 + wave;    // ((n*7 + i)*4 + jg)
    if (u >= nunits) return;

    const int n   = u / UNITS_PER_ROI;
    const int rem = u - n * UNITS_PER_ROI;
    const int i   = rem >> 2;
    const int jg  = rem & 3;
    const int j0  = jg * 2;                   // first col bin of this group
    const int jcnt = (jg < JGROUPS - 1) ? 2 : 1;

    // ROI corners: truncating float->int cast, matching jnp astype(int32)
    const float4 roi = reinterpret_cast<const float4*>(rois)[n];
    const int h0 = (int)((float)FH * roi.x);
    const int w0 = (int)((float)FW * roi.y);
    const int h1 = (int)((float)FH * roi.z);
    const int w1 = (int)((float)FW * roi.w);
    const int rh = h1 - h0;
    const int rw = w1 - w0;
    const int hstep = rh / POOL;
    const int wstep = rw / POOL;

    // row-bin bounds (region-relative) + empty-bin adjustment
    int sh = i * hstep;
    int eh = (i < POOL - 1) ? (i + 1) * hstep : rh;
    if (sh == eh) { if (eh < rh) eh += 1; else sh -= 1; }
    const int r0 = max(0, h0 + sh);
    const int r1 = min(FH, h0 + eh);

    // col bounds for this wave's (up to) 2 bins; only constant-indexed.
    int c0[2], c1[2];
#pragma unroll
    for (int t = 0; t < 2; ++t) {
        const int j = j0 + t;
        if (j < POOL) {
            int sw = j * wstep;
            int ew = (j < POOL - 1) ? (j + 1) * wstep : rw;
            if (sw == ew) { if (ew < rw) ew += 1; else sw -= 1; }
            c0[t] = max(0, w0 + sw);
            c1[t] = min(FW, w0 + ew);
        } else {
            c0[t] = 0; c1[t] = 0;            // empty range, acc unused
        }
    }

    const int rowstride = FW * CSTRIDE;
    const vf4* base = reinterpret_cast<const vf4*>(src)
                    + (size_t)chunk * CHSTRIDE + lane;

    vf4 acc[2];
#pragma unroll
    for (int t = 0; t < 2; ++t) {
        acc[t].x = -INFINITY; acc[t].y = -INFINITY;
        acc[t].z = -INFINITY; acc[t].w = -INFINITY;
    }

    for (int r = r0; r < r1; ++r) {
        const vf4* rowp = base + (size_t)r * rowstride;
#pragma unroll
        for (int t = 0; t < 2; ++t) {
            int c = c0[t];
            const int ce = c1[t];
            for (; c + 1 < ce; c += 2) {
                vf4 a  = rowp[c * CSTRIDE];
                vf4 b2 = rowp[(c + 1) * CSTRIDE];
                acc[t] = vmax4(acc[t], vmax4(a, b2));
            }
            if (c < ce) {
                acc[t] = vmax4(acc[t], rowp[c * CSTRIDE]);
            }
        }
    }

    // output layout is unchanged: [N,7,7,1024], f4-within-cell = chunk*64+lane
    const int of4 = chunk * F4C + lane;
    vf4* o = reinterpret_cast<vf4*>(out) + (size_t)(n * 49 + i * 7 + j0) * FC4 + of4;
    __builtin_nontemporal_store(acc[0], o);
    if (jcnt == 2) {
        __builtin_nontemporal_store(acc[1], o + (size_t)FC4);
    }
}

extern "C" void kernel_launch(void* const* d_in, const int* in_sizes, int n_in,
                              void* d_out, int out_size, void* d_ws, size_t ws_size,
                              hipStream_t stream) {
    const float* features = (const float*)d_in[0];  // [1,50,50,1024]
    const float* rois     = (const float*)d_in[1];  // [N,4]
    float* out            = (float*)d_out;          // [N,7,7,1024]
    const int N = in_sizes[1] / 4;

    const int nunits = N * UNITS_PER_ROI;           // 8400 units
    dim3 grid(((nunits + 3) / 4) * CHUNKS);         // 8400 blocks
    dim3 block(256);

    const size_t needT = (size_t)CHUNKS * CHSLAB * 4 * sizeof(float); // 10.24 MB
    if (ws_size >= needT) {
        float* fmT = (float*)d_ws;
        // 625 cell-groups x 4 chunks; same-stream ordering, no sync needed
        chunkmajor_kernel<<<dim3((NCELLS / 4) * CHUNKS), block, 0, stream>>>(features, fmT);
        roipool_kernel<F4C, CHSLAB><<<grid, block, 0, stream>>>(fmT, rois, out, nunits);
    } else {
        // fallback: direct layout (round-2 behavior)
        roipool_kernel<FC4, F4C><<<grid, block, 0, stream>>>(features, rois, out, nunits);
    }
}

// Round 5
// 98.580 us; speedup vs baseline: 1.0481x; 1.0296x over previous
//
#include <hip/hip_runtime.h>
#include <math.h>

#define POOL 7
#define FH 50
#define FW 50
#define FC 1024
#define FC4 (FC / 4)        // 256 vf4 per spatial cell
#define CHUNKS 4            // channel chunks; 64 vf4 (256 ch) per chunk
#define F4C 64              // vf4 per cell per chunk (one wave-wide load)
#define RS (FW * FC4)       // row stride in vf4
#define JGROUPS 4           // column-bin groups: {0,1},{2,3},{4,5},{6}
#define UNITS_PER_ROI (POOL * JGROUPS)   // 28

typedef float vf4 __attribute__((ext_vector_type(4)));

static __device__ __forceinline__ vf4 vmax4(vf4 a, vf4 b) {
    vf4 r;
    r.x = fmaxf(a.x, b.x);
    r.y = fmaxf(a.y, b.y);
    r.z = fmaxf(a.z, b.z);
    r.w = fmaxf(a.w, b.w);
    return r;
}

// Specialized inner loops for wstep = W (compile-time), valid when
// wstep >= 1: col bins j<6 have width EXACTLY W (no empty-bin adjustment,
// no clamping since ROI is inside [0,1] -> region inside the feature map).
//
// jg < 3 (bin pair): 2 rows x 2W cols of unconditional independent loads
// per iteration (4/8/12 in flight), a0/a1 split at compile-time column W.
// Odd-row tail: single row of 2W loads.
//
// jg == 3 (last bin, runtime width bw = rw-6W in [W, W+6]): fixed W+6
// loads per row with the column index CLAMPED to bw-1 — duplicate loads
// are idempotent under max and hit L1; keeps the load list unconditional.
template<int W>
static __device__ __forceinline__ void pool_w(
    const vf4* __restrict__ base,    // fm4 + (chunk*F4C + lane)
    int r0, int nrows, int w0, int rw, int jg,
    vf4& a0, vf4& a1)
{
    if (jg < 3) {
        const int c0 = w0 + (jg * 2) * W;
        const vf4* p = base + (size_t)r0 * RS + (size_t)c0 * FC4;
        int t = 0;
        for (; t + 2 <= nrows; t += 2) {
            vf4 v0[2 * W], v1[2 * W];
#pragma unroll
            for (int k = 0; k < 2 * W; ++k) v0[k] = p[k * FC4];
#pragma unroll
            for (int k = 0; k < 2 * W; ++k) v1[k] = p[RS + k * FC4];
#pragma unroll
            for (int k = 0; k < W; ++k) a0 = vmax4(a0, vmax4(v0[k], v1[k]));
#pragma unroll
            for (int k = W; k < 2 * W; ++k) a1 = vmax4(a1, vmax4(v0[k], v1[k]));
            p += 2 * RS;
        }
        if (t < nrows) {
            vf4 v0[2 * W];
#pragma unroll
            for (int k = 0; k < 2 * W; ++k) v0[k] = p[k * FC4];
#pragma unroll
            for (int k = 0; k < W; ++k) a0 = vmax4(a0, v0[k]);
#pragma unroll
            for (int k = W; k < 2 * W; ++k) a1 = vmax4(a1, v0[k]);
        }
    } else {
        const int bw = rw - 6 * W;          // [W, W+6]
        const int c0 = w0 + 6 * W;
        const vf4* p = base + (size_t)r0 * RS + (size_t)c0 * FC4;
        for (int r = 0; r < nrows; ++r) {
            vf4 v[W + 6];
#pragma unroll
            for (int k = 0; k < W + 6; ++k) {
                const int kc = (k < bw) ? k : (bw - 1);   // clamp: dup-max ok
                v[k] = p[kc * FC4];
            }
#pragma unroll
            for (int k = 0; k < W + 6; ++k) a0 = vmax4(a0, v[k]);
            p += RS;
        }
    }
}

// Grid/decomposition = round 2 exactly (proven best): 8400 blocks,
// wave = (roi n, row-bin i, col-bin-pair jg, chunk); chunk = b&3 is pinned
// per XCD (b%8 round-robin) so each XCD's 2.56 MB fm slice stays
// L2-resident (FETCH_SIZE ~8.3 MB confirmed). Only the inner loop changed:
// compile-time-specialized branch-free deep-MLP load bodies (see pool_w).
__global__ __launch_bounds__(256) void roipool_kernel(
    const float* __restrict__ fm,     // [FH, FW, FC]
    const float* __restrict__ rois,   // [N, 4] (y1, x1, y2, x2) normalized
    float* __restrict__ out,          // [N, 7, 7, FC]
    int nunits)                       // N * POOL * JGROUPS units
{
    const int b     = blockIdx.x;
    const int chunk = b & (CHUNKS - 1);       // pinned per XCD
    const int wave  = threadIdx.x >> 6;
    const int lane  = threadIdx.x & 63;
    const int u     = (b >> 2) * 4 + wave;    // ((n*7 + i)*4 + jg)
    if (u >= nunits) return;

    const int n   = u / UNITS_PER_ROI;
    const int rem = u - n * UNITS_PER_ROI;
    const int i   = rem >> 2;
    const int jg  = rem & 3;
    const int j0  = jg * 2;
    const int jcnt = (jg < JGROUPS - 1) ? 2 : 1;

    // ROI corners: truncating float->int cast, matching jnp astype(int32)
    const float4 roi = reinterpret_cast<const float4*>(rois)[n];
    const int h0 = (int)((float)FH * roi.x);
    const int w0 = (int)((float)FW * roi.y);
    const int h1 = (int)((float)FH * roi.z);
    const int w1 = (int)((float)FW * roi.w);
    const int rh = h1 - h0;
    const int rw = w1 - w0;
    const int hstep = rh / POOL;
    const int wstep = rw / POOL;

    const int f4 = chunk * F4C + lane;        // [0, 256)
    const vf4* base = reinterpret_cast<const vf4*>(fm) + f4;

    vf4 a0 = {-INFINITY, -INFINITY, -INFINITY, -INFINITY};
    vf4 a1 = a0;

    if (hstep >= 1 && wstep >= 1 && wstep <= 3) {
        // ---- specialized fast paths (always taken for this input dist) ----
        // row-bin: width exactly hstep for i<6; last bin rh-6*hstep (>=1)
        const int r0    = h0 + i * hstep;
        const int nrows = (i < POOL - 1) ? hstep : (rh - 6 * hstep);
        switch (wstep) {
            case 1: pool_w<1>(base, r0, nrows, w0, rw, jg, a0, a1); break;
            case 2: pool_w<2>(base, r0, nrows, w0, rw, jg, a0, a1); break;
            default: pool_w<3>(base, r0, nrows, w0, rw, jg, a0, a1); break;
        }
    } else {
        // ---- generic fallback (degenerate ROIs): round-2 code ----
        int sh = i * hstep;
        int eh = (i < POOL - 1) ? (i + 1) * hstep : rh;
        if (sh == eh) { if (eh < rh) eh += 1; else sh -= 1; }
        const int r0 = max(0, h0 + sh);
        const int r1 = min(FH, h0 + eh);

        int c0[2], c1[2];
#pragma unroll
        for (int t = 0; t < 2; ++t) {
            const int j = j0 + t;
            if (j < POOL) {
                int sw = j * wstep;
                int ew = (j < POOL - 1) ? (j + 1) * wstep : rw;
                if (sw == ew) { if (ew < rw) ew += 1; else sw -= 1; }
                c0[t] = max(0, w0 + sw);
                c1[t] = min(FW, w0 + ew);
            } else {
                c0[t] = 0; c1[t] = 0;
            }
        }
        for (int r = r0; r < r1; ++r) {
            const vf4* rowp = base + (size_t)r * RS;
#pragma unroll
            for (int t = 0; t < 2; ++t) {
                vf4 acc = (t == 0) ? a0 : a1;
                for (int c = c0[t]; c < c1[t]; ++c) {
                    acc = vmax4(acc, rowp[c * FC4]);
                }
                if (t == 0) a0 = acc; else a1 = acc;
            }
        }
    }

    vf4* o = reinterpret_cast<vf4*>(out) + (size_t)(n * 49 + i * 7 + j0) * FC4 + f4;
    __builtin_nontemporal_store(a0, o);
    if (jcnt == 2) {
        __builtin_nontemporal_store(a1, o + (size_t)FC4);
    }
}

extern "C" void kernel_launch(void* const* d_in, const int* in_sizes, int n_in,
                              void* d_out, int out_size, void* d_ws, size_t ws_size,
                              hipStream_t stream) {
    const float* features = (const float*)d_in[0];  // [1,50,50,1024]
    const float* rois     = (const float*)d_in[1];  // [N,4]
    float* out            = (float*)d_out;          // [N,7,7,1024]
    const int N = in_sizes[1] / 4;

    const int nunits = N * UNITS_PER_ROI;           // 8400 units
    dim3 grid(((nunits + 3) / 4) * CHUNKS);         // 8400 blocks
    dim3 block(256);
    roipool_kernel<<<grid, block, 0, stream>>>(features, rois, out, nunits);
}